// Round 1
// baseline (1931.055 us; speedup 1.0000x reference)
//
#include <hip/hip_runtime.h>
#include <hip/hip_bf16.h>

// Problem constants (HunYuan MoE V1): T=B*S=2048 tokens, HID=2048, FF=4096,
// 8 experts top-2 + shared MLP. All inputs fp32; output fp32 [2,1024,2048].
#define T_TOK 2048
#define HID   2048
#define FF    4096
#define NE    8

typedef __bf16 bf16_t;
typedef bf16_t bf16x8 __attribute__((ext_vector_type(8)));
typedef float  f32x4  __attribute__((ext_vector_type(4)));

// GEMM tiling: 128x128 tile, BK=64, 4 waves (2x2), each wave 64x64 via
// 4x4 grid of 16x16x32 bf16 MFMAs. LDS rows padded +8 bf16 (16B) so the
// 16-lane fragment reads land on rotating banks (2-way aliasing = free).
static constexpr int BM  = 128;
static constexpr int BN  = 128;
static constexpr int BK  = 64;
static constexpr int LDK = BK + 8;   // 72 bf16 = 144 B row stride (16B-aligned)

// ---------------------------------------------------------------------------
// Router: one wave per token. fp32 logits -> softmax -> top2 -> renormalize.
// Emits per-expert buckets of pair ids p = 2*t + slot and combine weights.
// ---------------------------------------------------------------------------
__global__ __launch_bounds__(256) void router_kernel(
    const float* __restrict__ x, const float* __restrict__ wg,
    int* __restrict__ counts, int* __restrict__ plist, float* __restrict__ wlist)
{
    const int wave = threadIdx.x >> 6;
    const int lane = threadIdx.x & 63;
    const int t = blockIdx.x * 4 + wave;

    const float* xp = x + (size_t)t * HID;
    float xr[32];
#pragma unroll
    for (int i = 0; i < 32; i++) xr[i] = xp[lane + 64 * i];

    float lg[NE];
#pragma unroll
    for (int e = 0; e < NE; e++) {
        const float* w = wg + e * HID;
        float s = 0.f;
#pragma unroll
        for (int i = 0; i < 32; i++) s += xr[i] * w[lane + 64 * i];
#pragma unroll
        for (int off = 32; off > 0; off >>= 1) s += __shfl_xor(s, off, 64);
        lg[e] = s;
    }

    float mx = lg[0];
#pragma unroll
    for (int e = 1; e < NE; e++) mx = fmaxf(mx, lg[e]);
    float p[NE];
#pragma unroll
    for (int e = 0; e < NE; e++) p[e] = __expf(lg[e] - mx);

    // top-1 then top-2; strict '>' keeps lowest index on ties (jax top_k order)
    int i1 = 0; float p1 = p[0];
#pragma unroll
    for (int e = 1; e < NE; e++) if (p[e] > p1) { p1 = p[e]; i1 = e; }
    int i2 = -1; float p2 = -1.f;
#pragma unroll
    for (int e = 0; e < NE; e++) if (e != i1 && p[e] > p2) { p2 = p[e]; i2 = e; }
    const float inv = 1.f / (p1 + p2);   // softmax denom cancels in renorm

    if (lane == 0) {
        int pos = atomicAdd(&counts[i1], 1);
        plist[i1 * T_TOK + pos] = t * 2;
        wlist[i1 * T_TOK + pos] = p1 * inv;
        pos = atomicAdd(&counts[i2], 1);
        plist[i2 * T_TOK + pos] = t * 2 + 1;
        wlist[i2 * T_TOK + pos] = p2 * inv;
    }
}

// ---------------------------------------------------------------------------
// Fused gate+up GEMM. z = 0..7 experts (gathered rows), z = 8 shared (all T).
// A = x fp32 [T,HID] (convert->bf16 in staging), B = W[F,HID] fp32 (NT: K
// contiguous for both operands). Epilogue: H[p, f] = bf16(silu(g)*u).
// H rows: expert pairs at p (0..4095), shared tokens at 4096+t.
// ---------------------------------------------------------------------------
__global__ __launch_bounds__(256, 2) void gateup_kernel(
    const float* __restrict__ x,
    const float* __restrict__ ex_gate, const float* __restrict__ ex_up,
    const float* __restrict__ sh_gate, const float* __restrict__ sh_up,
    const int* __restrict__ counts, const int* __restrict__ plist,
    bf16_t* __restrict__ H)
{
    const int z = blockIdx.z;
    const int count = (z == NE) ? T_TOK : counts[z];
    const int m0 = blockIdx.y * BM;
    if (m0 >= count) return;
    const int n0 = blockIdx.x * BN;

    const float* Bg = (z == NE) ? sh_gate : ex_gate + (size_t)z * FF * HID;
    const float* Bu = (z == NE) ? sh_up   : ex_up   + (size_t)z * FF * HID;

    __shared__ __align__(16) bf16_t As [BM * LDK];
    __shared__ __align__(16) bf16_t Bgs[BN * LDK];
    __shared__ __align__(16) bf16_t Bus[BN * LDK];
    __shared__ int prow[BM];   // H row per local row
    __shared__ int arow[BM];   // x row per local row

    const int tid = threadIdx.x;
    for (int r = tid; r < BM; r += 256) {
        int m = m0 + r;
        int pr, ar;
        if (z == NE) { pr = 4096 + m; ar = m; }
        else {
            int mm = (m < count) ? m : (count - 1);   // clamp tail rows
            pr = plist[z * T_TOK + mm];
            ar = pr >> 1;
        }
        prow[r] = pr; arow[r] = ar;
    }
    __syncthreads();

    const int wave = tid >> 6, lane = tid & 63;
    const int wr = (wave >> 1) * 64, wc = (wave & 1) * 64;
    const int lr = lane & 15;            // fragment row/col within 16
    const int lk = (lane >> 4) * 8;      // k chunk within 32

    f32x4 accg[4][4] = {};
    f32x4 accu[4][4] = {};

    // staging map: thread -> (row = tid/2, 32-col half = tid&1)
    const int srow = tid >> 1;
    const int shalf = (tid & 1) * 32;
    const float* aptr = x  + (size_t)arow[srow] * HID + shalf;
    const float* gptr = Bg + (size_t)(n0 + srow) * HID + shalf;
    const float* uptr = Bu + (size_t)(n0 + srow) * HID + shalf;
    bf16_t* adst = As  + srow * LDK + shalf;
    bf16_t* gdst = Bgs + srow * LDK + shalf;
    bf16_t* udst = Bus + srow * LDK + shalf;

    for (int k0 = 0; k0 < HID; k0 += BK) {
#pragma unroll
        for (int i = 0; i < 4; i++) {
            float4 a0 = ((const float4*)(aptr + k0))[2 * i];
            float4 a1 = ((const float4*)(aptr + k0))[2 * i + 1];
            bf16x8 ha;
            ha[0] = (bf16_t)a0.x; ha[1] = (bf16_t)a0.y; ha[2] = (bf16_t)a0.z; ha[3] = (bf16_t)a0.w;
            ha[4] = (bf16_t)a1.x; ha[5] = (bf16_t)a1.y; ha[6] = (bf16_t)a1.z; ha[7] = (bf16_t)a1.w;
            *(bf16x8*)(adst + 8 * i) = ha;

            float4 g0 = ((const float4*)(gptr + k0))[2 * i];
            float4 g1 = ((const float4*)(gptr + k0))[2 * i + 1];
            bf16x8 hg;
            hg[0] = (bf16_t)g0.x; hg[1] = (bf16_t)g0.y; hg[2] = (bf16_t)g0.z; hg[3] = (bf16_t)g0.w;
            hg[4] = (bf16_t)g1.x; hg[5] = (bf16_t)g1.y; hg[6] = (bf16_t)g1.z; hg[7] = (bf16_t)g1.w;
            *(bf16x8*)(gdst + 8 * i) = hg;

            float4 u0 = ((const float4*)(uptr + k0))[2 * i];
            float4 u1 = ((const float4*)(uptr + k0))[2 * i + 1];
            bf16x8 hu;
            hu[0] = (bf16_t)u0.x; hu[1] = (bf16_t)u0.y; hu[2] = (bf16_t)u0.z; hu[3] = (bf16_t)u0.w;
            hu[4] = (bf16_t)u1.x; hu[5] = (bf16_t)u1.y; hu[6] = (bf16_t)u1.z; hu[7] = (bf16_t)u1.w;
            *(bf16x8*)(udst + 8 * i) = hu;
        }
        __syncthreads();

#pragma unroll
        for (int kk = 0; kk < 2; kk++) {
            bf16x8 af[4], bg[4], bu[4];
#pragma unroll
            for (int i = 0; i < 4; i++)
                af[i] = *(const bf16x8*)(As + (wr + 16 * i + lr) * LDK + kk * 32 + lk);
#pragma unroll
            for (int j = 0; j < 4; j++) {
                bg[j] = *(const bf16x8*)(Bgs + (wc + 16 * j + lr) * LDK + kk * 32 + lk);
                bu[j] = *(const bf16x8*)(Bus + (wc + 16 * j + lr) * LDK + kk * 32 + lk);
            }
#pragma unroll
            for (int i = 0; i < 4; i++)
#pragma unroll
                for (int j = 0; j < 4; j++) {
                    accg[i][j] = __builtin_amdgcn_mfma_f32_16x16x32_bf16(af[i], bg[j], accg[i][j], 0, 0, 0);
                    accu[i][j] = __builtin_amdgcn_mfma_f32_16x16x32_bf16(af[i], bu[j], accu[i][j], 0, 0, 0);
                }
        }
        __syncthreads();
    }

    // epilogue: h = silu(g)*u -> bf16 H[p, col]
    const int q = lane >> 4;
#pragma unroll
    for (int i = 0; i < 4; i++) {
#pragma unroll
        for (int r = 0; r < 4; r++) {
            int row = wr + 16 * i + q * 4 + r;
            if (m0 + row < count) {
                bf16_t* hb = H + (size_t)prow[row] * FF + n0 + wc + lr;
#pragma unroll
                for (int j = 0; j < 4; j++) {
                    float g = accg[i][j][r], u = accu[i][j][r];
                    float h = g * (1.f / (1.f + __expf(-g))) * u;
                    hb[16 * j] = (bf16_t)h;
                }
            }
        }
    }
}

// ---------------------------------------------------------------------------
// Down projection. A = H bf16 [rows, FF], B = Wd [HID, FF] fp32 (NT).
// Epilogue scales by router weight and atomicAdds into out[t, :] (zeroed).
// ---------------------------------------------------------------------------
__global__ __launch_bounds__(256, 2) void down_kernel(
    const bf16_t* __restrict__ H,
    const float* __restrict__ ex_down, const float* __restrict__ sh_down,
    const int* __restrict__ counts, const int* __restrict__ plist,
    const float* __restrict__ wlist,
    float* __restrict__ out)
{
    const int z = blockIdx.z;
    const int count = (z == NE) ? T_TOK : counts[z];
    const int m0 = blockIdx.y * BM;
    if (m0 >= count) return;
    const int n0 = blockIdx.x * BN;

    const float* Bd = (z == NE) ? sh_down : ex_down + (size_t)z * HID * FF;

    __shared__ __align__(16) bf16_t As[BM * LDK];
    __shared__ __align__(16) bf16_t Bs[BN * LDK];
    __shared__ int   hrow[BM];
    __shared__ int   trow[BM];
    __shared__ float wrow[BM];

    const int tid = threadIdx.x;
    for (int r = tid; r < BM; r += 256) {
        int m = m0 + r;
        if (z == NE) { hrow[r] = 4096 + m; trow[r] = m; wrow[r] = 1.f; }
        else {
            int mm = (m < count) ? m : (count - 1);
            int pp = plist[z * T_TOK + mm];
            hrow[r] = pp; trow[r] = pp >> 1; wrow[r] = wlist[z * T_TOK + mm];
        }
    }
    __syncthreads();

    const int wave = tid >> 6, lane = tid & 63;
    const int wr = (wave >> 1) * 64, wc = (wave & 1) * 64;
    const int lr = lane & 15;
    const int lk = (lane >> 4) * 8;

    f32x4 acc[4][4] = {};

    const int srow = tid >> 1;
    const int shalf = (tid & 1) * 32;
    const bf16_t* aptr = H  + (size_t)hrow[srow] * FF + shalf;
    const float*  bptr = Bd + (size_t)(n0 + srow) * FF + shalf;
    bf16_t* adst = As + srow * LDK + shalf;
    bf16_t* bdst = Bs + srow * LDK + shalf;

    for (int k0 = 0; k0 < FF; k0 += BK) {
#pragma unroll
        for (int i = 0; i < 4; i++)
            *(bf16x8*)(adst + 8 * i) = *(const bf16x8*)(aptr + k0 + 8 * i);
#pragma unroll
        for (int i = 0; i < 4; i++) {
            float4 b0 = ((const float4*)(bptr + k0))[2 * i];
            float4 b1 = ((const float4*)(bptr + k0))[2 * i + 1];
            bf16x8 hb;
            hb[0] = (bf16_t)b0.x; hb[1] = (bf16_t)b0.y; hb[2] = (bf16_t)b0.z; hb[3] = (bf16_t)b0.w;
            hb[4] = (bf16_t)b1.x; hb[5] = (bf16_t)b1.y; hb[6] = (bf16_t)b1.z; hb[7] = (bf16_t)b1.w;
            *(bf16x8*)(bdst + 8 * i) = hb;
        }
        __syncthreads();

#pragma unroll
        for (int kk = 0; kk < 2; kk++) {
            bf16x8 af[4], bf[4];
#pragma unroll
            for (int i = 0; i < 4; i++)
                af[i] = *(const bf16x8*)(As + (wr + 16 * i + lr) * LDK + kk * 32 + lk);
#pragma unroll
            for (int j = 0; j < 4; j++)
                bf[j] = *(const bf16x8*)(Bs + (wc + 16 * j + lr) * LDK + kk * 32 + lk);
#pragma unroll
            for (int i = 0; i < 4; i++)
#pragma unroll
                for (int j = 0; j < 4; j++)
                    acc[i][j] = __builtin_amdgcn_mfma_f32_16x16x32_bf16(af[i], bf[j], acc[i][j], 0, 0, 0);
        }
        __syncthreads();
    }

    const int q = lane >> 4;
#pragma unroll
    for (int i = 0; i < 4; i++) {
#pragma unroll
        for (int r = 0; r < 4; r++) {
            int row = wr + 16 * i + q * 4 + r;
            if (m0 + row < count) {
                float w = wrow[row];
                float* ob = out + (size_t)trow[row] * HID + n0 + wc + lr;
#pragma unroll
                for (int j = 0; j < 4; j++)
                    atomicAdd(ob + 16 * j, w * acc[i][j][r]);
            }
        }
    }
}

// ---------------------------------------------------------------------------
// ws layout: [0,64) counts | [256,..) plist 8x2048 int | wlist 8x2048 float |
// H bf16 [6144, FF]  (rows 0..4095 expert pairs, 4096..6143 shared tokens)
// total ~50.5 MB
// ---------------------------------------------------------------------------
extern "C" void kernel_launch(void* const* d_in, const int* in_sizes, int n_in,
                              void* d_out, int out_size, void* d_ws, size_t ws_size,
                              hipStream_t stream)
{
    const float* x       = (const float*)d_in[0];
    const float* wg      = (const float*)d_in[1];
    const float* sh_gate = (const float*)d_in[2];
    const float* sh_up   = (const float*)d_in[3];
    const float* sh_down = (const float*)d_in[4];
    const float* ex_gate = (const float*)d_in[5];
    const float* ex_up   = (const float*)d_in[6];
    const float* ex_down = (const float*)d_in[7];
    float* out = (float*)d_out;

    char* ws = (char*)d_ws;
    int*    counts = (int*)ws;
    int*    plist  = (int*)(ws + 256);
    float*  wlist  = (float*)(ws + 256 + NE * T_TOK * 4);
    bf16_t* H      = (bf16_t*)(ws + 256 + 2 * NE * T_TOK * 4);

    hipMemsetAsync(counts, 0, 64, stream);
    hipMemsetAsync(d_out, 0, (size_t)out_size * sizeof(float), stream);

    router_kernel<<<T_TOK / 4, 256, 0, stream>>>(x, wg, counts, plist, wlist);
    gateup_kernel<<<dim3(FF / BN, T_TOK / BM, NE + 1), 256, 0, stream>>>(
        x, ex_gate, ex_up, sh_gate, sh_up, counts, plist, H);
    down_kernel<<<dim3(HID / BN, T_TOK / BM, NE + 1), 256, 0, stream>>>(
        H, ex_down, sh_down, counts, plist, wlist, out);
}